// Round 22
// baseline (1213.438 us; speedup 1.0000x reference)
//
#include <hip/hip_runtime.h>
#include <hip/hip_fp16.h>
#include <float.h>
#include <math.h>

#define BB 2
#define CC 128
#define CPAD (CC+4)  // 16B-aligned rows for float4 LDS reads
#define NN 4096
#define KNB 32
#define KSEL 48
#define GN 4
#define PR 4         // k_proj rows per block
#define MSEL 2048
#define NDROP 2048
#define CHUNKSZ 1024
#define NCHUNK 128   // NN*KNB / CHUNKSZ per batch
#define TJ 16        // gather j-tile
#define KNNTHREADS 512

// ---------------- workspace layout (bytes) ----------------
#define WS_WTQ    0
#define WS_WTV    (WS_WTQ + CC*CC*4)
#define WS_WTK    (WS_WTV + CC*CC*4)                 // float[CC*CC] (Wk transposed)
#define WS_SQF    (WS_WTK + CC*CC*4)                 // float[BB*NN]
#define WS_XT     (WS_SQF + BB*NN*4)                 // float[BB*NN*CC] (x transposed)
#define WS_QT     (WS_XT  + BB*NN*CC*4)              // float[BB*NN*CC]
#define WS_VXT    (WS_QT  + BB*NN*CC*4)              // float[BB*NN*CC]
#define WS_KNN    (WS_VXT + BB*NN*CC*4)              // int
#define WS_ATTNF  (WS_KNN + BB*NN*KNB*4)             // float
#define WS_STD    (WS_ATTNF + BB*NN*KNB*4)           // float[BB*NN]
#define WS_SCORE  (WS_STD + BB*NN*4)                 // float[BB*NN]
#define WS_COUNTS (WS_SCORE + BB*NN*4)
#define WS_OFF    (WS_COUNTS + BB*NN*4)
#define WS_SLOTS  (WS_OFF + BB*NN*4)
#define WS_CHUNK  (WS_SLOTS + BB*NN*KNB*4)           // int[BB][NCHUNK][NN] = 4MB
#define WS_SELDS  (WS_CHUNK + BB*NCHUNK*NN*4)
#define WS_SELDR  (WS_SELDS + BB*MSEL*4)
#define WS_END    (WS_SELDR + BB*NDROP*4)

// ---------------- output layout (floats) ----------------
#define OUT_XDS  0
#define OUT_IDX  (BB*CC*MSEL)
#define OUT_XDR  (OUT_IDX + BB*MSEL)
#define OUT_IDXD (OUT_XDR + BB*CC*NDROP)

// XLA:CPU-style sequential reduction over 32 contiguous fp32 (unfused adds).
__device__ __forceinline__ float seq32(const float* a) {
    float acc = a[0];
    #pragma unroll
    for (int i = 1; i < 32; ++i) acc = __fadd_rn(acc, a[i]);
    return acc;
}

// XLA lowers exp -> libm expf (nearly correctly rounded): emulate via double.
__device__ __forceinline__ float xla_expf(float x) {
    return (float)exp((double)x);
}

__global__ void k_transposeW(const float* __restrict__ Wq, const float* __restrict__ Wv,
                             const float* __restrict__ Wk,
                             float* __restrict__ WTq, float* __restrict__ WTv,
                             float* __restrict__ WTk) {
    int c = blockIdx.x, o = threadIdx.x;
    WTq[c*CC + o] = Wq[o*CC + c];
    WTv[c*CC + o] = Wv[o*CC + c];
    WTk[c*CC + o] = Wk[o*CC + c];
}

// x [b][c][n] -> xT [b][n][c] (LDS tile transpose; values untouched)
__global__ __launch_bounds__(256) void k_transposeX(const float* __restrict__ x,
                                                    float* __restrict__ xT) {
    __shared__ float t[32][33];
    int b  = blockIdx.z;
    int n0 = blockIdx.x * 32;
    int c0 = blockIdx.y * 32;
    int tx = threadIdx.x & 31, ty = threadIdx.x >> 5;  // 32 x 8
    const float* xb = x + (size_t)b*CC*NN;
    for (int r = ty; r < 32; r += 8)
        t[r][tx] = xb[(size_t)(c0+r)*NN + n0 + tx];
    __syncthreads();
    float* xo = xT + (size_t)b*NN*CC;
    for (int r = ty; r < 32; r += 8)
        xo[(size_t)(n0+r)*CC + c0 + tx] = t[tx][r];
}

// sqF: fp32 sequential over c (exact ref-emu; reads xT row contiguously).
__global__ void k_sq(const float* __restrict__ xT, float* __restrict__ sqF) {
    int i = blockIdx.x*blockDim.x + threadIdx.x;
    if (i >= BB*NN) return;
    const float* row = xT + (size_t)i*CC;
    float sf = 0.f;
    for (int c = 0; c < CC; ++c)
        sf = __fadd_rn(sf, __fmul_rn(row[c], row[c]));
    sqF[i] = sf;
}

// q: XLA-emu (sequential over c, FMA) — FROZEN per-row chain. PR rows per
// block amortize the 128KB weight reads 4x (verified green).
__global__ __launch_bounds__(CC) void k_proj(const float* __restrict__ xT,
                                             const float* __restrict__ WTq,
                                             const float* __restrict__ WTv,
                                             float* __restrict__ qT,
                                             float* __restrict__ vxT) {
    int bn0 = blockIdx.x * PR;
    int o = threadIdx.x;
    __shared__ float xs[PR][CC];
    #pragma unroll
    for (int r = 0; r < PR; ++r)
        xs[r][o] = xT[(size_t)(bn0+r)*CC + o];
    __syncthreads();
    float aq[PR], av[PR];
    #pragma unroll
    for (int r = 0; r < PR; ++r) { aq[r] = 0.f; av[r] = 0.f; }
    for (int c = 0; c < CC; ++c) {
        float wq = WTq[c*CC + o];
        float wv = WTv[c*CC + o];
        #pragma unroll
        for (int r = 0; r < PR; ++r) {
            float xv = xs[r][c];
            aq[r] = fmaf(wq, xv, aq[r]);
            av[r] = fmaf(wv, xv, av[r]);
        }
    }
    #pragma unroll
    for (int r = 0; r < PR; ++r) {
        size_t base = (size_t)(bn0+r)*CC + o;
        qT[base] = aq[r]; vxT[base] = av[r];
    }
}

// KNN v7: dist buffer in fp16 (LDS 69->37KB => 4 blocks/CU, full 32 waves/CU).
// fp16 only gates the top-KSEL SUPERSET (margin: rank gap ~2.0 >> fp16 noise
// ~0.12; KSEL widened 40->48); final top-32 order comes from the exact
// ref-emulated fp32 re-rank (FROZEN). XCD swizzle kept.
__global__ __launch_bounds__(KNNTHREADS) void k_knn(const float* __restrict__ x,
                                                    const float* __restrict__ xT,
                                                    const float* __restrict__ sqF,
                                                    int* __restrict__ knn) {
    __shared__ float  xs[GN][CC];
    __shared__ __half dist[GN][NN];
    __shared__ int    candIdx[GN][KSEL];
    __shared__ float  candDist[GN][KSEL];
    int blk = blockIdx.x;
    blk = (blk & 7) * ((BB*NN/GN) >> 3) + (blk >> 3);   // bijective XCD swizzle
    int b  = blk / (NN/GN);
    int n0 = (blk % (NN/GN)) * GN;
    int tid = threadIdx.x;
    const float* xb  = x  + (size_t)b*CC*NN;
    const float* xbT = xT + (size_t)b*NN*CC;
    const float* sqf = sqF + b*NN;
    if (tid < GN*CC) {
        int g = tid / CC, c = tid % CC;
        xs[g][c] = xbT[(size_t)(n0+g)*CC + c];
    }
    __syncthreads();
    // ---- gram: thread owns m in [8*tid, 8*tid+8) as 2 float4 chunks ----
    float4 acc[GN][2];
    #pragma unroll
    for (int g = 0; g < GN; ++g)
        #pragma unroll
        for (int u = 0; u < 2; ++u)
            acc[g][u] = make_float4(0.f, 0.f, 0.f, 0.f);
    int m0 = tid * 8;
    #pragma unroll 4
    for (int c = 0; c < CC; ++c) {
        float q0 = xs[0][c], q1 = xs[1][c], q2 = xs[2][c], q3 = xs[3][c];
        const float4* row = (const float4*)(xb + (size_t)c*NN + m0);
        #pragma unroll
        for (int u = 0; u < 2; ++u) {
            float4 xv = row[u];
            acc[0][u].x += q0*xv.x; acc[0][u].y += q0*xv.y; acc[0][u].z += q0*xv.z; acc[0][u].w += q0*xv.w;
            acc[1][u].x += q1*xv.x; acc[1][u].y += q1*xv.y; acc[1][u].z += q1*xv.z; acc[1][u].w += q1*xv.w;
            acc[2][u].x += q2*xv.x; acc[2][u].y += q2*xv.y; acc[2][u].z += q2*xv.z; acc[2][u].w += q2*xv.w;
            acc[3][u].x += q3*xv.x; acc[3][u].y += q3*xv.y; acc[3][u].z += q3*xv.z; acc[3][u].w += q3*xv.w;
        }
    }
    {
        float sqn[GN] = { sqf[n0+0], sqf[n0+1], sqf[n0+2], sqf[n0+3] };
        const float4* sqm4 = (const float4*)(sqf + m0);
        #pragma unroll
        for (int u = 0; u < 2; ++u) {
            float4 sm = sqm4[u];
            #pragma unroll
            for (int g = 0; g < GN; ++g) {
                float dx = sqn[g] + sm.x - 2.f*acc[g][u].x;
                float dy = sqn[g] + sm.y - 2.f*acc[g][u].y;
                float dz = sqn[g] + sm.z - 2.f*acc[g][u].z;
                float dw = sqn[g] + sm.w - 2.f*acc[g][u].w;
                *(__half2*)&dist[g][m0 + 4*u]     = __floats2half2_rn(dx, dy);
                *(__half2*)&dist[g][m0 + 4*u + 2] = __floats2half2_rn(dz, dw);
            }
        }
    }
    __syncthreads();
    // ---- selection on waves 0..GN-1 (lane owns m = lane+64i); fp32 compares
    //      of fp16 values; tie -> lower index (deterministic) ----
    int wid = tid >> 6, lane = tid & 63;
    if (wid < GN) {
        __half* dr = dist[wid];
        const __half HMAX = __float2half_rn(65504.0f);
        float gmv[8]; int gmi[8];
        #pragma unroll
        for (int gi = 0; gi < 8; ++gi) {
            float bv = FLT_MAX; int bi = NN;
            #pragma unroll
            for (int i2 = 0; i2 < 8; ++i2) {
                int m = lane + 64*(gi*8 + i2);
                float v = __half2float(dr[m]);
                if (v < bv) { bv = v; bi = m; }
            }
            gmv[gi] = bv; gmi[gi] = bi;
        }
        for (int kk = 0; kk < KSEL; ++kk) {
            float lv = gmv[0]; int li = gmi[0];
            #pragma unroll
            for (int gi = 1; gi < 8; ++gi)
                if (gmv[gi] < lv || (gmv[gi] == lv && gmi[gi] < li)) { lv = gmv[gi]; li = gmi[gi]; }
            float bv = lv; int bi = li;
            for (int off = 32; off > 0; off >>= 1) {
                float ov = __shfl_xor(bv, off);
                int   oi = __shfl_xor(bi, off);
                if (ov < bv || (ov == bv && oi < bi)) { bv = ov; bi = oi; }
            }
            if (lane == 0) candIdx[wid][kk] = bi;
            if ((bi & 63) == lane) {
                dr[bi] = HMAX;
                int gsel = (bi >> 6) >> 3;
                #pragma unroll
                for (int GI = 0; GI < 8; ++GI) if (GI == gsel) {
                    float bv2 = FLT_MAX; int bi2 = NN;
                    #pragma unroll
                    for (int i2 = 0; i2 < 8; ++i2) {
                        int m = lane + 64*(GI*8 + i2);
                        float v = __half2float(dr[m]);
                        if (v < bv2 || (v == bv2 && m < bi2)) { bv2 = v; bi2 = m; }
                    }
                    gmv[GI] = bv2; gmi[GI] = bi2;
                }
            }
        }
    }
    __syncthreads();
    // ---- re-rank by ref-emulated fp32 dist (sequential unfused; FROZEN) ----
    int g = wid, j = lane;
    if (g < GN && j < KSEL) {
        int m = candIdx[g][j];
        const float* colm = xbT + (size_t)m*CC;
        float acc2 = 0.f;
        for (int c = 0; c < CC; ++c)
            acc2 = __fadd_rn(acc2, __fmul_rn(xs[g][c], colm[c]));
        candDist[g][j] = __fsub_rn(__fadd_rn(sqf[n0+g], sqf[m]), __fmul_rn(2.0f, acc2));
    }
    __syncthreads();
    if (g < GN && j < KSEL) {
        float dme = candDist[g][j]; int ime = candIdx[g][j];
        int rank = 0;
        for (int t = 0; t < KSEL; ++t) {
            float dt = candDist[g][t]; int it = candIdx[g][t];
            if (dt < dme || (dt == dme && it < ime)) ++rank;
        }
        if (rank < KNB)
            knn[((size_t)b*NN + n0 + g)*KNB + rank] = ime;
    }
}

// XLA-emu energy kernel, FROZEN arithmetic (round-21 layout: shared nb/kmat
// buffer, 8 blocks/CU; XCD swizzle).
__global__ __launch_bounds__(CC) void k_energy(const float* __restrict__ xT,
                                               const float* __restrict__ qT,
                                               const float* __restrict__ WTk,
                                               const int* __restrict__ knn,
                                               float* __restrict__ attnF,
                                               float* __restrict__ stdF) {
    int bn = blockIdx.x;
    bn = (bn & 7) * ((BB*NN) >> 3) + (bn >> 3);   // bijective XCD swizzle
    int b = bn / NN;
    int o = threadIdx.x;
    __shared__ float xn[CC];
    __shared__ float qs[CC];
    __shared__ int   mIdx[KNB];
    __shared__ float buf[KNB][CPAD];   // nb, then kmat
    __shared__ float es[KNB];
    const float* xbT = xT + (size_t)b*NN*CC;
    xn[o] = xT[(size_t)bn*CC + o];
    qs[o] = qT[(size_t)bn*CC + o];
    if (o < KNB) mIdx[o] = knn[(size_t)bn*KNB + o];
    __syncthreads();
    #pragma unroll
    for (int kk = 0; kk < KNB; ++kk)
        buf[kk][o] = __fsub_rn(xbT[(size_t)mIdx[kk]*CC + o], xn[o]);
    __syncthreads();
    float acc[KNB];
    #pragma unroll
    for (int kk = 0; kk < KNB; ++kk) acc[kk] = 0.f;
    for (int c4 = 0; c4 < CC/4; ++c4) {
        int c = c4*4;
        float w0 = WTk[(c+0)*CC + o];
        float w1 = WTk[(c+1)*CC + o];
        float w2 = WTk[(c+2)*CC + o];
        float w3 = WTk[(c+3)*CC + o];
        #pragma unroll
        for (int kk = 0; kk < KNB; ++kk) {
            float4 n4 = *(const float4*)&buf[kk][c];
            float a = acc[kk];
            a = fmaf(w0, n4.x, a);
            a = fmaf(w1, n4.y, a);
            a = fmaf(w2, n4.z, a);
            a = fmaf(w3, n4.w, a);
            acc[kk] = a;
        }
    }
    __syncthreads();   // all nb reads done before overwrite
    #pragma unroll
    for (int kk = 0; kk < KNB; ++kk) buf[kk][o] = acc[kk];   // now kmat
    __syncthreads();
    if (o < KNB) {
        float e = 0.f;
        for (int d = 0; d < CC; ++d)
            e = fmaf(qs[d], buf[o][d], e);
        es[o] = __fdiv_rn(e, __fsqrt_rn(128.0f));
    }
    __syncthreads();
    if (o == 0) {
        float mx = es[0];
        #pragma unroll
        for (int kk = 1; kk < KNB; ++kk) mx = fmaxf(mx, es[kk]);
        float p[KNB], a[KNB], d2[KNB];
        #pragma unroll
        for (int kk = 0; kk < KNB; ++kk)
            p[kk] = xla_expf(__fsub_rn(es[kk], mx));
        float s = seq32(p);
        #pragma unroll
        for (int kk = 0; kk < KNB; ++kk) {
            a[kk] = __fdiv_rn(p[kk], s);
            attnF[(size_t)bn*KNB + kk] = a[kk];
        }
        float mean = __fdiv_rn(seq32(a), 32.0f);
        #pragma unroll
        for (int kk = 0; kk < KNB; ++kk) {
            float dd = __fsub_rn(a[kk], mean);
            d2[kk] = __fmul_rn(dd, dd);
        }
        float var = __fdiv_rn(seq32(d2), 32.0f);
        stdF[bn] = __fsqrt_rn(var);
    }
}

__global__ __launch_bounds__(256) void k_scan(const int* __restrict__ counts, int* __restrict__ off) {
    int b = blockIdx.x;
    const int* c = counts + b*NN;
    int* o = off + b*NN;
    __shared__ int part[256];
    __shared__ int partScan[256];
    int tid = threadIdx.x;
    int base = tid*16;
    int s = 0;
    for (int i = 0; i < 16; ++i) s += c[base+i];
    part[tid] = s;
    __syncthreads();
    if (tid == 0) { int a = 0; for (int i = 0; i < 256; ++i) { partScan[i] = a; a += part[i]; } }
    __syncthreads();
    int a = partScan[tid];
    for (int i = 0; i < 16; ++i) { o[base+i] = a; a += c[base+i]; }
}

// Per-chunk histogram over segment ids (deterministic; LDS atomics).
__global__ __launch_bounds__(256) void k_chunkcount(const int* __restrict__ knn,
                                                    int* __restrict__ chunkCnt) {
    __shared__ int hist[NN];
    int b = blockIdx.x / NCHUNK, p = blockIdx.x % NCHUNK;
    int tid = threadIdx.x;
    for (int i = tid; i < NN; i += 256) hist[i] = 0;
    __syncthreads();
    const int* kb = knn + (size_t)b*NN*KNB + (size_t)p*CHUNKSZ;
    for (int i = tid; i < CHUNKSZ; i += 256)
        atomicAdd(&hist[kb[i]], 1);
    __syncthreads();
    int* row = chunkCnt + ((size_t)b*NCHUNK + p)*NN;
    for (int i = tid; i < NN; i += 256) row[i] = hist[i];
}

// Per (b,m): exclusive scan of chunkCnt over chunks (in place); final total
// -> counts (replaces global-atomic k_count; integer-exact).
__global__ __launch_bounds__(256) void k_chunkscan(int* __restrict__ chunkCnt,
                                                   int* __restrict__ counts) {
    int i = blockIdx.x*blockDim.x + threadIdx.x;
    if (i >= BB*NN) return;
    int b = i / NN, m = i % NN;
    int running = 0;
    for (int p = 0; p < NCHUNK; ++p) {
        size_t idx = ((size_t)b*NCHUNK + p)*NN + m;
        int t = chunkCnt[idx];
        chunkCnt[idx] = running;
        running += t;
    }
    counts[i] = running;
}

// Stable fill, 1024 threads (one element each); integer-exact ranks.
__global__ __launch_bounds__(CHUNKSZ) void k_fill2(const int* __restrict__ knn,
                                                   const int* __restrict__ off,
                                                   const int* __restrict__ chunkCnt,
                                                   int* __restrict__ slots) {
    __shared__ int mv[CHUNKSZ];
    int b = blockIdx.x / NCHUNK, p = blockIdx.x % NCHUNK;
    int i = threadIdx.x;
    const int* kb = knn + (size_t)b*NN*KNB + (size_t)p*CHUNKSZ;
    mv[i] = kb[i];
    __syncthreads();
    const int* cbase = chunkCnt + ((size_t)b*NCHUNK + p)*NN;
    const int* ob    = off + b*NN;
    int* sb = slots + (size_t)b*NN*KNB;
    int m = mv[i];
    int rank = 0;
    for (int j = 0; j < i; ++j) rank += (mv[j] == m);
    sb[ob[m] + cbase[m] + rank] = p*CHUNKSZ + i;
}

// Segment sum in ascending (n,k) order, sequential fp32 unfused adds.
__global__ void k_segsum(const int* __restrict__ off, const int* __restrict__ counts,
                         const int* __restrict__ slots, const float* __restrict__ attn,
                         float* __restrict__ score) {
    int i = blockIdx.x*blockDim.x + threadIdx.x;
    if (i >= BB*NN) return;
    int b = i / NN;
    int o = off[i], cnt = counts[i];
    const int* s = slots + (size_t)b*NN*KNB + o;
    const float* ab = attn + (size_t)b*NN*KNB;
    float acc = 0.f;
    for (int a = 0; a < cnt; ++a) acc = __fadd_rn(acc, ab[s[a]]);
    score[i] = acc;
}

// Merged bitonic sorts: blocks [0,BB) sort score DESC; [BB,2BB) sort std ASC.
__global__ __launch_bounds__(256) void k_topsort2(const float* __restrict__ score,
                                                  const float* __restrict__ stdv,
                                                  float* __restrict__ out,
                                                  int* __restrict__ selds,
                                                  int* __restrict__ seldr) {
    int blk = blockIdx.x;
    bool desc = blk < BB;
    int b = desc ? blk : blk - BB;
    const float* val = (desc ? score : stdv) + b*NN;
    __shared__ float v[NN];
    __shared__ int  id[NN];
    for (int i = threadIdx.x; i < NN; i += 256) { v[i] = val[i]; id[i] = i; }
    __syncthreads();
    for (int k = 2; k <= NN; k <<= 1) {
        for (int j = k >> 1; j > 0; j >>= 1) {
            for (int i = threadIdx.x; i < NN; i += 256) {
                int ixj = i ^ j;
                if (ixj > i) {
                    float va = v[i], vb = v[ixj];
                    int ia = id[i], ib = id[ixj];
                    bool before = desc ? (va > vb || (va == vb && ia < ib))
                                       : (va < vb || (va == vb && ia < ib));
                    bool up = ((i & k) == 0);
                    if (up ? !before : before) {
                        v[i] = vb; v[ixj] = va; id[i] = ib; id[ixj] = ia;
                    }
                }
            }
            __syncthreads();
        }
    }
    float* idx_out = out + (desc ? OUT_IDX : OUT_IDXD) + b*MSEL;
    int*   sel_out = (desc ? selds : seldr) + b*MSEL;
    for (int i = threadIdx.x; i < MSEL; i += 256) {
        idx_out[i] = (float)id[i];
        sel_out[i] = id[i];
    }
}

// Tiled gather: block handles TJ selected columns; LDS tile then coalesced writes.
__global__ __launch_bounds__(CC) void k_gather(const float* __restrict__ vxT,
                                               const float* __restrict__ attn,
                                               const int* __restrict__ knn,
                                               const int* __restrict__ sel_ds,
                                               const int* __restrict__ sel_dr,
                                               float* __restrict__ out) {
    __shared__ float a_s[TJ][KNB];
    __shared__ int   m_s[TJ][KNB];
    __shared__ int   nsel_s[TJ];
    __shared__ float tile[TJ][CC];
    int blk = blockIdx.x;
    int c = threadIdx.x;
    const int blocksPerSel = BB*MSEL/TJ;
    bool dropped = false;
    if (blk >= blocksPerSel) { dropped = true; blk -= blocksPerSel; }
    int b  = blk / (MSEL/TJ);
    int j0 = (blk % (MSEL/TJ)) * TJ;
    const int* sel = (dropped ? sel_dr : sel_ds) + b*MSEL;
    if (c < TJ) nsel_s[c] = sel[j0 + c];
    __syncthreads();
    for (int i = c; i < TJ*KNB; i += CC) {
        int j = i / KNB, k = i % KNB;
        int ns = nsel_s[j];
        a_s[j][k] = attn[((size_t)b*NN + ns)*KNB + k];
        m_s[j][k] = knn [((size_t)b*NN + ns)*KNB + k];
    }
    __syncthreads();
    const float* vb = vxT + (size_t)b*NN*CC;
    for (int j = 0; j < TJ; ++j) {
        float vn = vb[(size_t)nsel_s[j]*CC + c];
        float acc = 0.f;
        #pragma unroll
        for (int k = 0; k < KNB; ++k)
            acc += a_s[j][k] * (vb[(size_t)m_s[j][k]*CC + c] - vn);
        tile[j][c] = acc;
    }
    __syncthreads();
    float* obase = out + (dropped ? OUT_XDR : OUT_XDS);
    for (int w = c; w < TJ*CC; w += CC) {
        int j = w & (TJ-1);
        int cc = w >> 4;   // log2(TJ)=4
        obase[((size_t)b*CC + cc)*MSEL + j0 + j] = tile[j][cc];
    }
}

extern "C" void kernel_launch(void* const* d_in, const int* in_sizes, int n_in,
                              void* d_out, int out_size, void* d_ws, size_t ws_size,
                              hipStream_t stream) {
    const float* x  = (const float*)d_in[0];
    const float* Wq = (const float*)d_in[1];
    const float* Wk = (const float*)d_in[2];
    const float* Wv = (const float*)d_in[3];
    float* out = (float*)d_out;
    char* ws = (char*)d_ws;

    float*  WTq    = (float*) (ws + WS_WTQ);
    float*  WTv    = (float*) (ws + WS_WTV);
    float*  WTk    = (float*) (ws + WS_WTK);
    float*  sqF    = (float*) (ws + WS_SQF);
    float*  xT     = (float*) (ws + WS_XT);
    float*  qT     = (float*) (ws + WS_QT);
    float*  vxT    = (float*) (ws + WS_VXT);
    int*    knn    = (int*)   (ws + WS_KNN);
    float*  attnF  = (float*) (ws + WS_ATTNF);
    float*  stdF   = (float*) (ws + WS_STD);
    float*  score  = (float*) (ws + WS_SCORE);
    int*    counts = (int*)   (ws + WS_COUNTS);
    int*    off    = (int*)   (ws + WS_OFF);
    int*    slots  = (int*)   (ws + WS_SLOTS);
    int*    chunkC = (int*)   (ws + WS_CHUNK);
    int*    selds  = (int*)   (ws + WS_SELDS);
    int*    seldr  = (int*)   (ws + WS_SELDR);

    hipLaunchKernelGGL(k_transposeW, dim3(CC), dim3(CC), 0, stream, Wq, Wv, Wk, WTq, WTv, WTk);
    hipLaunchKernelGGL(k_transposeX, dim3(NN/32, CC/32, BB), dim3(256), 0, stream, x, xT);
    hipLaunchKernelGGL(k_sq, dim3((BB*NN + 255)/256), dim3(256), 0, stream, xT, sqF);
    hipLaunchKernelGGL(k_proj, dim3(BB*NN/PR), dim3(CC), 0, stream, xT, WTq, WTv, qT, vxT);
    hipLaunchKernelGGL(k_knn, dim3(BB*NN/GN), dim3(KNNTHREADS), 0, stream, x, xT, sqF, knn);
    hipLaunchKernelGGL(k_energy, dim3(BB*NN), dim3(CC), 0, stream, xT, qT, WTk, knn, attnF, stdF);

    hipLaunchKernelGGL(k_chunkcount, dim3(BB*NCHUNK), dim3(256), 0, stream, knn, chunkC);
    hipLaunchKernelGGL(k_chunkscan, dim3((BB*NN + 255)/256), dim3(256), 0, stream, chunkC, counts);
    hipLaunchKernelGGL(k_scan, dim3(BB), dim3(256), 0, stream, counts, off);
    hipLaunchKernelGGL(k_fill2, dim3(BB*NCHUNK), dim3(CHUNKSZ), 0, stream, knn, off, chunkC, slots);
    hipLaunchKernelGGL(k_segsum, dim3((BB*NN + 255)/256), dim3(256), 0, stream, off, counts, slots, attnF, score);

    hipLaunchKernelGGL(k_topsort2, dim3(2*BB), dim3(256), 0, stream, score, stdF, out, selds, seldr);

    hipLaunchKernelGGL(k_gather, dim3(BB*(MSEL + NDROP)/TJ), dim3(CC), 0, stream, vxT, attnF, knn, selds, seldr, out);
}

// Round 23
// 1161.610 us; speedup vs baseline: 1.0446x; 1.0446x over previous
//
#include <hip/hip_runtime.h>
#include <float.h>
#include <math.h>

#define BB 2
#define CC 128
#define CPAD (CC+4)  // 16B-aligned rows for float4 LDS reads
#define NN 4096
#define KNB 32
#define KSEL 40
#define GN 4
#define PR 4         // k_proj rows per block
#define MSEL 2048
#define NDROP 2048
#define CHUNKSZ 1024
#define NCHUNK 128   // NN*KNB / CHUNKSZ per batch
#define TJ 16        // gather j-tile
#define KNNTHREADS 512

// ---------------- workspace layout (bytes) ----------------
#define WS_WTQ    0
#define WS_WTV    (WS_WTQ + CC*CC*4)
#define WS_WTK    (WS_WTV + CC*CC*4)                 // float[CC*CC] (Wk transposed)
#define WS_SQF    (WS_WTK + CC*CC*4)                 // float[BB*NN]
#define WS_XT     (WS_SQF + BB*NN*4)                 // float[BB*NN*CC] (x transposed)
#define WS_QT     (WS_XT  + BB*NN*CC*4)              // float[BB*NN*CC]
#define WS_VXT    (WS_QT  + BB*NN*CC*4)              // float[BB*NN*CC]
#define WS_KNN    (WS_VXT + BB*NN*CC*4)              // int
#define WS_ATTNF  (WS_KNN + BB*NN*KNB*4)             // float
#define WS_STD    (WS_ATTNF + BB*NN*KNB*4)           // float[BB*NN]
#define WS_SCORE  (WS_STD + BB*NN*4)                 // float[BB*NN]
#define WS_COUNTS (WS_SCORE + BB*NN*4)
#define WS_OFF    (WS_COUNTS + BB*NN*4)
#define WS_SLOTS  (WS_OFF + BB*NN*4)
#define WS_CHUNK  (WS_SLOTS + BB*NN*KNB*4)           // int[BB][NCHUNK][NN] = 4MB
#define WS_SELDS  (WS_CHUNK + BB*NCHUNK*NN*4)
#define WS_SELDR  (WS_SELDS + BB*MSEL*4)
#define WS_END    (WS_SELDR + BB*NDROP*4)

// ---------------- output layout (floats) ----------------
#define OUT_XDS  0
#define OUT_IDX  (BB*CC*MSEL)
#define OUT_XDR  (OUT_IDX + BB*MSEL)
#define OUT_IDXD (OUT_XDR + BB*CC*NDROP)

// XLA:CPU-style sequential reduction over 32 contiguous fp32 (unfused adds).
__device__ __forceinline__ float seq32(const float* a) {
    float acc = a[0];
    #pragma unroll
    for (int i = 1; i < 32; ++i) acc = __fadd_rn(acc, a[i]);
    return acc;
}

// XLA lowers exp -> libm expf (nearly correctly rounded): emulate via double.
__device__ __forceinline__ float xla_expf(float x) {
    return (float)exp((double)x);
}

__global__ void k_transposeW(const float* __restrict__ Wq, const float* __restrict__ Wv,
                             const float* __restrict__ Wk,
                             float* __restrict__ WTq, float* __restrict__ WTv,
                             float* __restrict__ WTk) {
    int c = blockIdx.x, o = threadIdx.x;
    WTq[c*CC + o] = Wq[o*CC + c];
    WTv[c*CC + o] = Wv[o*CC + c];
    WTk[c*CC + o] = Wk[o*CC + c];
}

// x [b][c][n] -> xT [b][n][c] (LDS tile transpose; values untouched)
__global__ __launch_bounds__(256) void k_transposeX(const float* __restrict__ x,
                                                    float* __restrict__ xT) {
    __shared__ float t[32][33];
    int b  = blockIdx.z;
    int n0 = blockIdx.x * 32;
    int c0 = blockIdx.y * 32;
    int tx = threadIdx.x & 31, ty = threadIdx.x >> 5;  // 32 x 8
    const float* xb = x + (size_t)b*CC*NN;
    for (int r = ty; r < 32; r += 8)
        t[r][tx] = xb[(size_t)(c0+r)*NN + n0 + tx];
    __syncthreads();
    float* xo = xT + (size_t)b*NN*CC;
    for (int r = ty; r < 32; r += 8)
        xo[(size_t)(n0+r)*CC + c0 + tx] = t[tx][r];
}

// sqF: fp32 sequential over c (exact ref-emu; reads xT row contiguously).
__global__ void k_sq(const float* __restrict__ xT, float* __restrict__ sqF) {
    int i = blockIdx.x*blockDim.x + threadIdx.x;
    if (i >= BB*NN) return;
    const float* row = xT + (size_t)i*CC;
    float sf = 0.f;
    for (int c = 0; c < CC; ++c)
        sf = __fadd_rn(sf, __fmul_rn(row[c], row[c]));
    sqF[i] = sf;
}

// q: XLA-emu (sequential over c, FMA) — FROZEN per-row chain. PR rows per
// block amortize the 128KB weight reads 4x (verified green).
__global__ __launch_bounds__(CC) void k_proj(const float* __restrict__ xT,
                                             const float* __restrict__ WTq,
                                             const float* __restrict__ WTv,
                                             float* __restrict__ qT,
                                             float* __restrict__ vxT) {
    int bn0 = blockIdx.x * PR;
    int o = threadIdx.x;
    __shared__ float xs[PR][CC];
    #pragma unroll
    for (int r = 0; r < PR; ++r)
        xs[r][o] = xT[(size_t)(bn0+r)*CC + o];
    __syncthreads();
    float aq[PR], av[PR];
    #pragma unroll
    for (int r = 0; r < PR; ++r) { aq[r] = 0.f; av[r] = 0.f; }
    for (int c = 0; c < CC; ++c) {
        float wq = WTq[c*CC + o];
        float wv = WTv[c*CC + o];
        #pragma unroll
        for (int r = 0; r < PR; ++r) {
            float xv = xs[r][c];
            aq[r] = fmaf(wq, xv, aq[r]);
            av[r] = fmaf(wv, xv, av[r]);
        }
    }
    #pragma unroll
    for (int r = 0; r < PR; ++r) {
        size_t base = (size_t)(bn0+r)*CC + o;
        qT[base] = aq[r]; vxT[base] = av[r];
    }
}

// KNN v5 (round-21 verified-best config: fp32 dist, KSEL=40, x4 unroll,
// XCD swizzle). fp16 dist (r22) gave no occupancy and cost +52us — reverted.
__global__ __launch_bounds__(KNNTHREADS) void k_knn(const float* __restrict__ x,
                                                    const float* __restrict__ xT,
                                                    const float* __restrict__ sqF,
                                                    int* __restrict__ knn) {
    __shared__ float xs[GN][CC];
    __shared__ float dist[GN][NN];
    __shared__ int   candIdx[GN][KSEL];
    __shared__ float candDist[GN][KSEL];
    int blk = blockIdx.x;
    blk = (blk & 7) * ((BB*NN/GN) >> 3) + (blk >> 3);   // bijective XCD swizzle
    int b  = blk / (NN/GN);
    int n0 = (blk % (NN/GN)) * GN;
    int tid = threadIdx.x;
    const float* xb  = x  + (size_t)b*CC*NN;
    const float* xbT = xT + (size_t)b*NN*CC;
    const float* sqf = sqF + b*NN;
    if (tid < GN*CC) {
        int g = tid / CC, c = tid % CC;
        xs[g][c] = xbT[(size_t)(n0+g)*CC + c];
    }
    __syncthreads();
    float4 acc[GN][2];
    #pragma unroll
    for (int g = 0; g < GN; ++g)
        #pragma unroll
        for (int u = 0; u < 2; ++u)
            acc[g][u] = make_float4(0.f, 0.f, 0.f, 0.f);
    int m0 = tid * 8;
    #pragma unroll 4
    for (int c = 0; c < CC; ++c) {
        float q0 = xs[0][c], q1 = xs[1][c], q2 = xs[2][c], q3 = xs[3][c];
        const float4* row = (const float4*)(xb + (size_t)c*NN + m0);
        #pragma unroll
        for (int u = 0; u < 2; ++u) {
            float4 xv = row[u];
            acc[0][u].x += q0*xv.x; acc[0][u].y += q0*xv.y; acc[0][u].z += q0*xv.z; acc[0][u].w += q0*xv.w;
            acc[1][u].x += q1*xv.x; acc[1][u].y += q1*xv.y; acc[1][u].z += q1*xv.z; acc[1][u].w += q1*xv.w;
            acc[2][u].x += q2*xv.x; acc[2][u].y += q2*xv.y; acc[2][u].z += q2*xv.z; acc[2][u].w += q2*xv.w;
            acc[3][u].x += q3*xv.x; acc[3][u].y += q3*xv.y; acc[3][u].z += q3*xv.z; acc[3][u].w += q3*xv.w;
        }
    }
    {
        float sqn0 = sqf[n0+0], sqn1 = sqf[n0+1], sqn2 = sqf[n0+2], sqn3 = sqf[n0+3];
        const float4* sqm4 = (const float4*)(sqf + m0);
        #pragma unroll
        for (int u = 0; u < 2; ++u) {
            float4 sm = sqm4[u];
            float4 d0, d1, d2, d3;
            d0.x = sqn0 + sm.x - 2.f*acc[0][u].x; d0.y = sqn0 + sm.y - 2.f*acc[0][u].y;
            d0.z = sqn0 + sm.z - 2.f*acc[0][u].z; d0.w = sqn0 + sm.w - 2.f*acc[0][u].w;
            d1.x = sqn1 + sm.x - 2.f*acc[1][u].x; d1.y = sqn1 + sm.y - 2.f*acc[1][u].y;
            d1.z = sqn1 + sm.z - 2.f*acc[1][u].z; d1.w = sqn1 + sm.w - 2.f*acc[1][u].w;
            d2.x = sqn2 + sm.x - 2.f*acc[2][u].x; d2.y = sqn2 + sm.y - 2.f*acc[2][u].y;
            d2.z = sqn2 + sm.z - 2.f*acc[2][u].z; d2.w = sqn2 + sm.w - 2.f*acc[2][u].w;
            d3.x = sqn3 + sm.x - 2.f*acc[3][u].x; d3.y = sqn3 + sm.y - 2.f*acc[3][u].y;
            d3.z = sqn3 + sm.z - 2.f*acc[3][u].z; d3.w = sqn3 + sm.w - 2.f*acc[3][u].w;
            *(float4*)&dist[0][m0 + 4*u] = d0;
            *(float4*)&dist[1][m0 + 4*u] = d1;
            *(float4*)&dist[2][m0 + 4*u] = d2;
            *(float4*)&dist[3][m0 + 4*u] = d3;
        }
    }
    __syncthreads();
    int wid = tid >> 6, lane = tid & 63;
    if (wid < GN) {
        float* dr = dist[wid];
        float gmv[8]; int gmi[8];
        #pragma unroll
        for (int gi = 0; gi < 8; ++gi) {
            float bv = FLT_MAX; int bi = NN;
            #pragma unroll
            for (int i2 = 0; i2 < 8; ++i2) {
                int m = lane + 64*(gi*8 + i2);
                float v = dr[m];
                if (v < bv) { bv = v; bi = m; }
            }
            gmv[gi] = bv; gmi[gi] = bi;
        }
        for (int kk = 0; kk < KSEL; ++kk) {
            float lv = gmv[0]; int li = gmi[0];
            #pragma unroll
            for (int gi = 1; gi < 8; ++gi)
                if (gmv[gi] < lv || (gmv[gi] == lv && gmi[gi] < li)) { lv = gmv[gi]; li = gmi[gi]; }
            float bv = lv; int bi = li;
            for (int off = 32; off > 0; off >>= 1) {
                float ov = __shfl_xor(bv, off);
                int   oi = __shfl_xor(bi, off);
                if (ov < bv || (ov == bv && oi < bi)) { bv = ov; bi = oi; }
            }
            if (lane == 0) candIdx[wid][kk] = bi;
            if ((bi & 63) == lane) {
                dr[bi] = FLT_MAX;
                int gsel = (bi >> 6) >> 3;
                #pragma unroll
                for (int GI = 0; GI < 8; ++GI) if (GI == gsel) {
                    float bv2 = FLT_MAX; int bi2 = NN;
                    #pragma unroll
                    for (int i2 = 0; i2 < 8; ++i2) {
                        int m = lane + 64*(GI*8 + i2);
                        float v = dr[m];
                        if (v < bv2 || (v == bv2 && m < bi2)) { bv2 = v; bi2 = m; }
                    }
                    gmv[GI] = bv2; gmi[GI] = bi2;
                }
            }
        }
    }
    __syncthreads();
    int g = wid, j = lane;
    if (g < GN && j < KSEL) {
        int m = candIdx[g][j];
        const float* colm = xbT + (size_t)m*CC;
        float acc2 = 0.f;
        for (int c = 0; c < CC; ++c)
            acc2 = __fadd_rn(acc2, __fmul_rn(xs[g][c], colm[c]));
        candDist[g][j] = __fsub_rn(__fadd_rn(sqf[n0+g], sqf[m]), __fmul_rn(2.0f, acc2));
    }
    __syncthreads();
    if (g < GN && j < KSEL) {
        float dme = candDist[g][j]; int ime = candIdx[g][j];
        int rank = 0;
        for (int t = 0; t < KSEL; ++t) {
            float dt = candDist[g][t]; int it = candIdx[g][t];
            if (dt < dme || (dt == dme && it < ime)) ++rank;
        }
        if (rank < KNB)
            knn[((size_t)b*NN + n0 + g)*KNB + rank] = ime;
    }
}

// XLA-emu energy kernel, FROZEN arithmetic (round-21 layout: shared nb/kmat
// buffer, 8 blocks/CU; XCD swizzle).
__global__ __launch_bounds__(CC) void k_energy(const float* __restrict__ xT,
                                               const float* __restrict__ qT,
                                               const float* __restrict__ WTk,
                                               const int* __restrict__ knn,
                                               float* __restrict__ attnF,
                                               float* __restrict__ stdF) {
    int bn = blockIdx.x;
    bn = (bn & 7) * ((BB*NN) >> 3) + (bn >> 3);   // bijective XCD swizzle
    int b = bn / NN;
    int o = threadIdx.x;
    __shared__ float xn[CC];
    __shared__ float qs[CC];
    __shared__ int   mIdx[KNB];
    __shared__ float buf[KNB][CPAD];   // nb, then kmat
    __shared__ float es[KNB];
    const float* xbT = xT + (size_t)b*NN*CC;
    xn[o] = xT[(size_t)bn*CC + o];
    qs[o] = qT[(size_t)bn*CC + o];
    if (o < KNB) mIdx[o] = knn[(size_t)bn*KNB + o];
    __syncthreads();
    #pragma unroll
    for (int kk = 0; kk < KNB; ++kk)
        buf[kk][o] = __fsub_rn(xbT[(size_t)mIdx[kk]*CC + o], xn[o]);
    __syncthreads();
    float acc[KNB];
    #pragma unroll
    for (int kk = 0; kk < KNB; ++kk) acc[kk] = 0.f;
    for (int c4 = 0; c4 < CC/4; ++c4) {
        int c = c4*4;
        float w0 = WTk[(c+0)*CC + o];
        float w1 = WTk[(c+1)*CC + o];
        float w2 = WTk[(c+2)*CC + o];
        float w3 = WTk[(c+3)*CC + o];
        #pragma unroll
        for (int kk = 0; kk < KNB; ++kk) {
            float4 n4 = *(const float4*)&buf[kk][c];
            float a = acc[kk];
            a = fmaf(w0, n4.x, a);
            a = fmaf(w1, n4.y, a);
            a = fmaf(w2, n4.z, a);
            a = fmaf(w3, n4.w, a);
            acc[kk] = a;
        }
    }
    __syncthreads();   // all nb reads done before overwrite
    #pragma unroll
    for (int kk = 0; kk < KNB; ++kk) buf[kk][o] = acc[kk];   // now kmat
    __syncthreads();
    if (o < KNB) {
        float e = 0.f;
        for (int d = 0; d < CC; ++d)
            e = fmaf(qs[d], buf[o][d], e);
        es[o] = __fdiv_rn(e, __fsqrt_rn(128.0f));
    }
    __syncthreads();
    if (o == 0) {
        float mx = es[0];
        #pragma unroll
        for (int kk = 1; kk < KNB; ++kk) mx = fmaxf(mx, es[kk]);
        float p[KNB], a[KNB], d2[KNB];
        #pragma unroll
        for (int kk = 0; kk < KNB; ++kk)
            p[kk] = xla_expf(__fsub_rn(es[kk], mx));
        float s = seq32(p);
        #pragma unroll
        for (int kk = 0; kk < KNB; ++kk) {
            a[kk] = __fdiv_rn(p[kk], s);
            attnF[(size_t)bn*KNB + kk] = a[kk];
        }
        float mean = __fdiv_rn(seq32(a), 32.0f);
        #pragma unroll
        for (int kk = 0; kk < KNB; ++kk) {
            float dd = __fsub_rn(a[kk], mean);
            d2[kk] = __fmul_rn(dd, dd);
        }
        float var = __fdiv_rn(seq32(d2), 32.0f);
        stdF[bn] = __fsqrt_rn(var);
    }
}

__global__ __launch_bounds__(256) void k_scan(const int* __restrict__ counts, int* __restrict__ off) {
    int b = blockIdx.x;
    const int* c = counts + b*NN;
    int* o = off + b*NN;
    __shared__ int part[256];
    __shared__ int partScan[256];
    int tid = threadIdx.x;
    int base = tid*16;
    int s = 0;
    for (int i = 0; i < 16; ++i) s += c[base+i];
    part[tid] = s;
    __syncthreads();
    if (tid == 0) { int a = 0; for (int i = 0; i < 256; ++i) { partScan[i] = a; a += part[i]; } }
    __syncthreads();
    int a = partScan[tid];
    for (int i = 0; i < 16; ++i) { o[base+i] = a; a += c[base+i]; }
}

// Per-chunk histogram over segment ids (deterministic; LDS atomics).
__global__ __launch_bounds__(256) void k_chunkcount(const int* __restrict__ knn,
                                                    int* __restrict__ chunkCnt) {
    __shared__ int hist[NN];
    int b = blockIdx.x / NCHUNK, p = blockIdx.x % NCHUNK;
    int tid = threadIdx.x;
    for (int i = tid; i < NN; i += 256) hist[i] = 0;
    __syncthreads();
    const int* kb = knn + (size_t)b*NN*KNB + (size_t)p*CHUNKSZ;
    for (int i = tid; i < CHUNKSZ; i += 256)
        atomicAdd(&hist[kb[i]], 1);
    __syncthreads();
    int* row = chunkCnt + ((size_t)b*NCHUNK + p)*NN;
    for (int i = tid; i < NN; i += 256) row[i] = hist[i];
}

// Per (b,m): exclusive scan of chunkCnt over chunks (in place); final total
// -> counts (replaces global-atomic k_count; integer-exact).
__global__ __launch_bounds__(256) void k_chunkscan(int* __restrict__ chunkCnt,
                                                   int* __restrict__ counts) {
    int i = blockIdx.x*blockDim.x + threadIdx.x;
    if (i >= BB*NN) return;
    int b = i / NN, m = i % NN;
    int running = 0;
    for (int p = 0; p < NCHUNK; ++p) {
        size_t idx = ((size_t)b*NCHUNK + p)*NN + m;
        int t = chunkCnt[idx];
        chunkCnt[idx] = running;
        running += t;
    }
    counts[i] = running;
}

// Stable fill, 1024 threads (one element each); integer-exact ranks.
__global__ __launch_bounds__(CHUNKSZ) void k_fill2(const int* __restrict__ knn,
                                                   const int* __restrict__ off,
                                                   const int* __restrict__ chunkCnt,
                                                   int* __restrict__ slots) {
    __shared__ int mv[CHUNKSZ];
    int b = blockIdx.x / NCHUNK, p = blockIdx.x % NCHUNK;
    int i = threadIdx.x;
    const int* kb = knn + (size_t)b*NN*KNB + (size_t)p*CHUNKSZ;
    mv[i] = kb[i];
    __syncthreads();
    const int* cbase = chunkCnt + ((size_t)b*NCHUNK + p)*NN;
    const int* ob    = off + b*NN;
    int* sb = slots + (size_t)b*NN*KNB;
    int m = mv[i];
    int rank = 0;
    for (int j = 0; j < i; ++j) rank += (mv[j] == m);
    sb[ob[m] + cbase[m] + rank] = p*CHUNKSZ + i;
}

// Segment sum in ascending (n,k) order, sequential fp32 unfused adds.
__global__ void k_segsum(const int* __restrict__ off, const int* __restrict__ counts,
                         const int* __restrict__ slots, const float* __restrict__ attn,
                         float* __restrict__ score) {
    int i = blockIdx.x*blockDim.x + threadIdx.x;
    if (i >= BB*NN) return;
    int b = i / NN;
    int o = off[i], cnt = counts[i];
    const int* s = slots + (size_t)b*NN*KNB + o;
    const float* ab = attn + (size_t)b*NN*KNB;
    float acc = 0.f;
    for (int a = 0; a < cnt; ++a) acc = __fadd_rn(acc, ab[s[a]]);
    score[i] = acc;
}

// Merged bitonic sorts: blocks [0,BB) sort score DESC; [BB,2BB) sort std ASC.
__global__ __launch_bounds__(256) void k_topsort2(const float* __restrict__ score,
                                                  const float* __restrict__ stdv,
                                                  float* __restrict__ out,
                                                  int* __restrict__ selds,
                                                  int* __restrict__ seldr) {
    int blk = blockIdx.x;
    bool desc = blk < BB;
    int b = desc ? blk : blk - BB;
    const float* val = (desc ? score : stdv) + b*NN;
    __shared__ float v[NN];
    __shared__ int  id[NN];
    for (int i = threadIdx.x; i < NN; i += 256) { v[i] = val[i]; id[i] = i; }
    __syncthreads();
    for (int k = 2; k <= NN; k <<= 1) {
        for (int j = k >> 1; j > 0; j >>= 1) {
            for (int i = threadIdx.x; i < NN; i += 256) {
                int ixj = i ^ j;
                if (ixj > i) {
                    float va = v[i], vb = v[ixj];
                    int ia = id[i], ib = id[ixj];
                    bool before = desc ? (va > vb || (va == vb && ia < ib))
                                       : (va < vb || (va == vb && ia < ib));
                    bool up = ((i & k) == 0);
                    if (up ? !before : before) {
                        v[i] = vb; v[ixj] = va; id[i] = ib; id[ixj] = ia;
                    }
                }
            }
            __syncthreads();
        }
    }
    float* idx_out = out + (desc ? OUT_IDX : OUT_IDXD) + b*MSEL;
    int*   sel_out = (desc ? selds : seldr) + b*MSEL;
    for (int i = threadIdx.x; i < MSEL; i += 256) {
        idx_out[i] = (float)id[i];
        sel_out[i] = id[i];
    }
}

// Tiled gather: block handles TJ selected columns; LDS tile then coalesced writes.
__global__ __launch_bounds__(CC) void k_gather(const float* __restrict__ vxT,
                                               const float* __restrict__ attn,
                                               const int* __restrict__ knn,
                                               const int* __restrict__ sel_ds,
                                               const int* __restrict__ sel_dr,
                                               float* __restrict__ out) {
    __shared__ float a_s[TJ][KNB];
    __shared__ int   m_s[TJ][KNB];
    __shared__ int   nsel_s[TJ];
    __shared__ float tile[TJ][CC];
    int blk = blockIdx.x;
    int c = threadIdx.x;
    const int blocksPerSel = BB*MSEL/TJ;
    bool dropped = false;
    if (blk >= blocksPerSel) { dropped = true; blk -= blocksPerSel; }
    int b  = blk / (MSEL/TJ);
    int j0 = (blk % (MSEL/TJ)) * TJ;
    const int* sel = (dropped ? sel_dr : sel_ds) + b*MSEL;
    if (c < TJ) nsel_s[c] = sel[j0 + c];
    __syncthreads();
    for (int i = c; i < TJ*KNB; i += CC) {
        int j = i / KNB, k = i % KNB;
        int ns = nsel_s[j];
        a_s[j][k] = attn[((size_t)b*NN + ns)*KNB + k];
        m_s[j][k] = knn [((size_t)b*NN + ns)*KNB + k];
    }
    __syncthreads();
    const float* vb = vxT + (size_t)b*NN*CC;
    for (int j = 0; j < TJ; ++j) {
        float vn = vb[(size_t)nsel_s[j]*CC + c];
        float acc = 0.f;
        #pragma unroll
        for (int k = 0; k < KNB; ++k)
            acc += a_s[j][k] * (vb[(size_t)m_s[j][k]*CC + c] - vn);
        tile[j][c] = acc;
    }
    __syncthreads();
    float* obase = out + (dropped ? OUT_XDR : OUT_XDS);
    for (int w = c; w < TJ*CC; w += CC) {
        int j = w & (TJ-1);
        int cc = w >> 4;   // log2(TJ)=4
        obase[((size_t)b*CC + cc)*MSEL + j0 + j] = tile[j][cc];
    }
}

extern "C" void kernel_launch(void* const* d_in, const int* in_sizes, int n_in,
                              void* d_out, int out_size, void* d_ws, size_t ws_size,
                              hipStream_t stream) {
    const float* x  = (const float*)d_in[0];
    const float* Wq = (const float*)d_in[1];
    const float* Wk = (const float*)d_in[2];
    const float* Wv = (const float*)d_in[3];
    float* out = (float*)d_out;
    char* ws = (char*)d_ws;

    float*  WTq    = (float*) (ws + WS_WTQ);
    float*  WTv    = (float*) (ws + WS_WTV);
    float*  WTk    = (float*) (ws + WS_WTK);
    float*  sqF    = (float*) (ws + WS_SQF);
    float*  xT     = (float*) (ws + WS_XT);
    float*  qT     = (float*) (ws + WS_QT);
    float*  vxT    = (float*) (ws + WS_VXT);
    int*    knn    = (int*)   (ws + WS_KNN);
    float*  attnF  = (float*) (ws + WS_ATTNF);
    float*  stdF   = (float*) (ws + WS_STD);
    float*  score  = (float*) (ws + WS_SCORE);
    int*    counts = (int*)   (ws + WS_COUNTS);
    int*    off    = (int*)   (ws + WS_OFF);
    int*    slots  = (int*)   (ws + WS_SLOTS);
    int*    chunkC = (int*)   (ws + WS_CHUNK);
    int*    selds  = (int*)   (ws + WS_SELDS);
    int*    seldr  = (int*)   (ws + WS_SELDR);

    hipLaunchKernelGGL(k_transposeW, dim3(CC), dim3(CC), 0, stream, Wq, Wv, Wk, WTq, WTv, WTk);
    hipLaunchKernelGGL(k_transposeX, dim3(NN/32, CC/32, BB), dim3(256), 0, stream, x, xT);
    hipLaunchKernelGGL(k_sq, dim3((BB*NN + 255)/256), dim3(256), 0, stream, xT, sqF);
    hipLaunchKernelGGL(k_proj, dim3(BB*NN/PR), dim3(CC), 0, stream, xT, WTq, WTv, qT, vxT);
    hipLaunchKernelGGL(k_knn, dim3(BB*NN/GN), dim3(KNNTHREADS), 0, stream, x, xT, sqF, knn);
    hipLaunchKernelGGL(k_energy, dim3(BB*NN), dim3(CC), 0, stream, xT, qT, WTk, knn, attnF, stdF);

    hipLaunchKernelGGL(k_chunkcount, dim3(BB*NCHUNK), dim3(256), 0, stream, knn, chunkC);
    hipLaunchKernelGGL(k_chunkscan, dim3((BB*NN + 255)/256), dim3(256), 0, stream, chunkC, counts);
    hipLaunchKernelGGL(k_scan, dim3(BB), dim3(256), 0, stream, counts, off);
    hipLaunchKernelGGL(k_fill2, dim3(BB*NCHUNK), dim3(CHUNKSZ), 0, stream, knn, off, chunkC, slots);
    hipLaunchKernelGGL(k_segsum, dim3((BB*NN + 255)/256), dim3(256), 0, stream, off, counts, slots, attnF, score);

    hipLaunchKernelGGL(k_topsort2, dim3(2*BB), dim3(256), 0, stream, score, stdF, out, selds, seldr);

    hipLaunchKernelGGL(k_gather, dim3(BB*(MSEL + NDROP)/TJ), dim3(CC), 0, stream, vxT, attnF, knn, selds, seldr, out);
}